// Round 3
// baseline (277.012 us; speedup 1.0000x reference)
//
#include <hip/hip_runtime.h>
#include <math.h>

#define S 8192
#define E 64
#define CAP 256
static const long long NOUT = (long long)S * E * CAP;  // 134,217,728 elems per output

typedef float f32x4 __attribute__((ext_vector_type(4)));

// ---------------------------------------------------------------------------
// Kernel A: per-row fp32 softmax + top-1/top-2 selection.
// One wave (64 lanes) per row; lane == expert index. 4 rows per block.
// ---------------------------------------------------------------------------
__global__ void softmax_top2(const float* __restrict__ in,
                             int* __restrict__ idx1, int* __restrict__ idx2,
                             float* __restrict__ w1, float* __restrict__ w2) {
    const int lane = threadIdx.x;          // 0..63, == expert id
    const int row  = blockIdx.x * 4 + threadIdx.y;

    float x = in[row * E + lane];

    // wave max
    float mx = x;
    #pragma unroll
    for (int o = 32; o > 0; o >>= 1) mx = fmaxf(mx, __shfl_xor(mx, o));

    float p = __expf(x - mx);
    float sum = p;
    #pragma unroll
    for (int o = 32; o > 0; o >>= 1) sum += __shfl_xor(sum, o);
    float prob = p / sum;

    // argmax on x (same order as prob), first-index tie-break like jnp.argmax
    float v = x; int idx = lane;
    #pragma unroll
    for (int o = 32; o > 0; o >>= 1) {
        float ov = __shfl_xor(v, o);
        int   oi = __shfl_xor(idx, o);
        if (ov > v || (ov == v && oi < idx)) { v = ov; idx = oi; }
    }
    const int i1 = idx;

    // top-2: mask out top-1, argmax again
    float x2 = (lane == i1) ? -INFINITY : x;
    v = x2; idx = lane;
    #pragma unroll
    for (int o = 32; o > 0; o >>= 1) {
        float ov = __shfl_xor(v, o);
        int   oi = __shfl_xor(idx, o);
        if (ov > v || (ov == v && oi < idx)) { v = ov; idx = oi; }
    }
    const int i2 = idx;

    const float pw1 = __shfl(prob, i1);
    const float pw2 = __shfl(prob, i2);

    if (lane == 0) {
        idx1[row] = i1;
        idx2[row] = i2;
        w1[row]   = pw1;
        w2[row]   = pw2;
    }
}

// ---------------------------------------------------------------------------
// Kernel B: exclusive rank per expert via ballot+popcount prefix.
// Block b owns expert b (64 blocks, 1 wave each). Pass 1 computes rank1 and,
// as a side effect, count1[e] (loop-carried base). Pass 2 computes rank2
// offset by count1[e] — per-expert-column offset, no inter-block dependency.
// ---------------------------------------------------------------------------
__global__ void rank_kernel(const int* __restrict__ idx1,
                            const int* __restrict__ idx2,
                            int* __restrict__ rank1, int* __restrict__ rank2) {
    const int e    = blockIdx.x;
    const int lane = threadIdx.x;
    const unsigned long long below = (lane == 0) ? 0ULL : ((1ULL << lane) - 1ULL);

    int base = 0;
    #pragma unroll 4
    for (int t0 = 0; t0 < S; t0 += 64) {
        const int t = t0 + lane;
        const int i = idx1[t];
        const unsigned long long m = __ballot(i == e);
        if (i == e) rank1[t] = base + __popcll(m & below);
        base += __popcll(m);
    }
    // base == count1[e] == sum(mask1[:, e])
    int base2 = base;
    #pragma unroll 4
    for (int t0 = 0; t0 < S; t0 += 64) {
        const int t = t0 + lane;
        const int i = idx2[t];
        const unsigned long long m = __ballot(i == e);
        if (i == e) rank2[t] = base2 + __popcll(m & below);
        base2 += __popcll(m);
    }
}

// ---------------------------------------------------------------------------
// Kernel C: fused zero-fill + sparse scatter. One block per token row.
// Each block streams its 64KB cb row + 64KB mask row with float4
// non-temporal stores, patching the <=2 nonzero elements in-register.
// ---------------------------------------------------------------------------
__global__ __launch_bounds__(256) void fill_scatter(
        const int* __restrict__ idx1, const int* __restrict__ idx2,
        const float* __restrict__ w1, const float* __restrict__ w2,
        const int* __restrict__ rank1, const int* __restrict__ rank2,
        float* __restrict__ out) {
    const int t = blockIdx.x;

    // row-scalar parameters (all lanes load same address -> broadcast)
    const int r1 = rank1[t];
    const int r2 = rank2[t];
    const int p1 = (r1 < CAP) ? idx1[t] * CAP + r1 : -1;   // elem pos in [0,16384)
    const int p2 = (r2 < CAP) ? idx2[t] * CAP + r2 : -1;
    const float v1 = w1[t];
    const float v2 = w2[t];
    const float m1 = (v1 != 0.0f) ? 1.0f : 0.0f;
    const float m2 = (v2 != 0.0f) ? 1.0f : 0.0f;

    float* __restrict__ cb = out + (long long)t * (E * CAP);
    float* __restrict__ mk = out + NOUT + (long long)t * (E * CAP);

    const int tid = threadIdx.x;
    const int q1 = p1 >> 2, j1 = p1 & 3;
    const int q2 = p2 >> 2, j2 = p2 & 3;

    #pragma unroll
    for (int i = 0; i < 16; ++i) {
        const int o = i * 1024 + tid * 4;      // element offset of this float4
        const int q = o >> 2;                  // float4 index
        f32x4 vz = {0.f, 0.f, 0.f, 0.f};
        f32x4 vm = {0.f, 0.f, 0.f, 0.f};
        if (q == q1) { vz[j1] = v1; vm[j1] = m1; }
        if (q == q2) { vz[j2] = v2; vm[j2] = m2; }
        __builtin_nontemporal_store(vz, (f32x4*)(cb + o));
        __builtin_nontemporal_store(vm, (f32x4*)(mk + o));
    }
}

extern "C" void kernel_launch(void* const* d_in, const int* in_sizes, int n_in,
                              void* d_out, int out_size, void* d_ws, size_t ws_size,
                              hipStream_t stream) {
    const float* in = (const float*)d_in[0];
    float* out = (float*)d_out;

    // workspace layout (8192 each): idx1, idx2, rank1, rank2, w1, w2
    int*   idx1  = (int*)d_ws;
    int*   idx2  = idx1 + S;
    int*   rank1 = idx2 + S;
    int*   rank2 = rank1 + S;
    float* w1    = (float*)(rank2 + S);
    float* w2    = w1 + S;

    softmax_top2<<<S / 4, dim3(64, 4), 0, stream>>>(in, idx1, idx2, w1, w2);
    rank_kernel<<<E, 64, 0, stream>>>(idx1, idx2, rank1, rank2);
    fill_scatter<<<S, 256, 0, stream>>>(idx1, idx2, w1, w2, rank1, rank2, out);
}

// Round 4
// 268.417 us; speedup vs baseline: 1.0320x; 1.0320x over previous
//
#include <hip/hip_runtime.h>
#include <math.h>

#define S 8192
#define E 64
#define CAP 256
static const long long NOUT = (long long)S * E * CAP;  // 134,217,728 elems per output

typedef float f32x4 __attribute__((ext_vector_type(4)));

// ---------------------------------------------------------------------------
// Kernel A: per-row fp32 softmax + top-1/top-2 selection.
// One wave (64 lanes) per row; lane == expert index. 4 rows per block.
// ---------------------------------------------------------------------------
__global__ void softmax_top2(const float* __restrict__ in,
                             int* __restrict__ idx1, int* __restrict__ idx2,
                             float* __restrict__ w1, float* __restrict__ w2) {
    const int lane = threadIdx.x;          // 0..63, == expert id
    const int row  = blockIdx.x * 4 + threadIdx.y;

    float x = in[row * E + lane];

    // wave max
    float mx = x;
    #pragma unroll
    for (int o = 32; o > 0; o >>= 1) mx = fmaxf(mx, __shfl_xor(mx, o));

    float p = __expf(x - mx);
    float sum = p;
    #pragma unroll
    for (int o = 32; o > 0; o >>= 1) sum += __shfl_xor(sum, o);
    float prob = p / sum;

    // argmax on x (same order as prob), first-index tie-break like jnp.argmax
    float v = x; int idx = lane;
    #pragma unroll
    for (int o = 32; o > 0; o >>= 1) {
        float ov = __shfl_xor(v, o);
        int   oi = __shfl_xor(idx, o);
        if (ov > v || (ov == v && oi < idx)) { v = ov; idx = oi; }
    }
    const int i1 = idx;

    // top-2: mask out top-1, argmax again
    float x2 = (lane == i1) ? -INFINITY : x;
    v = x2; idx = lane;
    #pragma unroll
    for (int o = 32; o > 0; o >>= 1) {
        float ov = __shfl_xor(v, o);
        int   oi = __shfl_xor(idx, o);
        if (ov > v || (ov == v && oi < idx)) { v = ov; idx = oi; }
    }
    const int i2 = idx;

    const float pw1 = __shfl(prob, i1);
    const float pw2 = __shfl(prob, i2);

    if (lane == 0) {
        idx1[row] = i1;
        idx2[row] = i2;
        w1[row]   = pw1;
        w2[row]   = pw2;
    }
}

// ---------------------------------------------------------------------------
// Kernel B: exclusive rank per expert via ballot+popcount prefix.
// Block b owns expert b (64 blocks, 1 wave each). Pass 1 computes rank1 and,
// as a side effect, count1[e] (loop-carried base). Pass 2 computes rank2
// offset by count1[e] — per-expert-column offset, no inter-block dependency.
// ---------------------------------------------------------------------------
__global__ void rank_kernel(const int* __restrict__ idx1,
                            const int* __restrict__ idx2,
                            int* __restrict__ rank1, int* __restrict__ rank2) {
    const int e    = blockIdx.x;
    const int lane = threadIdx.x;
    const unsigned long long below = (lane == 0) ? 0ULL : ((1ULL << lane) - 1ULL);

    int base = 0;
    #pragma unroll 4
    for (int t0 = 0; t0 < S; t0 += 64) {
        const int t = t0 + lane;
        const int i = idx1[t];
        const unsigned long long m = __ballot(i == e);
        if (i == e) rank1[t] = base + __popcll(m & below);
        base += __popcll(m);
    }
    // base == count1[e] == sum(mask1[:, e])
    int base2 = base;
    #pragma unroll 4
    for (int t0 = 0; t0 < S; t0 += 64) {
        const int t = t0 + lane;
        const int i = idx2[t];
        const unsigned long long m = __ballot(i == e);
        if (i == e) rank2[t] = base2 + __popcll(m & below);
        base2 += __popcll(m);
    }
}

// ---------------------------------------------------------------------------
// Kernel C: fused zero-fill + sparse scatter. One block per token row.
// Each block streams its 64KB cb row + 64KB mask row with float4 stores
// (through L2 — NT stores measured ~20% slower than rocclr fill here),
// patching the <=2 nonzero elements in-register.
// ---------------------------------------------------------------------------
__global__ __launch_bounds__(256) void fill_scatter(
        const int* __restrict__ idx1, const int* __restrict__ idx2,
        const float* __restrict__ w1, const float* __restrict__ w2,
        const int* __restrict__ rank1, const int* __restrict__ rank2,
        float* __restrict__ out) {
    const int t = blockIdx.x;

    // row-scalar parameters (all lanes load same address -> broadcast)
    const int r1 = rank1[t];
    const int r2 = rank2[t];
    const int p1 = (r1 < CAP) ? idx1[t] * CAP + r1 : -1;   // elem pos in [0,16384)
    const int p2 = (r2 < CAP) ? idx2[t] * CAP + r2 : -1;
    const float v1 = w1[t];
    const float v2 = w2[t];
    const float m1 = (v1 != 0.0f) ? 1.0f : 0.0f;
    const float m2 = (v2 != 0.0f) ? 1.0f : 0.0f;

    float* __restrict__ cb = out + (long long)t * (E * CAP);
    float* __restrict__ mk = out + NOUT + (long long)t * (E * CAP);

    const int tid = threadIdx.x;
    const int q1 = p1 >> 2, j1 = p1 & 3;
    const int q2 = p2 >> 2, j2 = p2 & 3;

    #pragma unroll
    for (int i = 0; i < 16; ++i) {
        const int o = i * 1024 + tid * 4;      // element offset of this float4
        const int q = o >> 2;                  // float4 index
        f32x4 vz = {0.f, 0.f, 0.f, 0.f};
        f32x4 vm = {0.f, 0.f, 0.f, 0.f};
        if (q == q1) { vz[j1] = v1; vm[j1] = m1; }
        if (q == q2) { vz[j2] = v2; vm[j2] = m2; }
        *(f32x4*)(cb + o) = vz;
        *(f32x4*)(mk + o) = vm;
    }
}

extern "C" void kernel_launch(void* const* d_in, const int* in_sizes, int n_in,
                              void* d_out, int out_size, void* d_ws, size_t ws_size,
                              hipStream_t stream) {
    const float* in = (const float*)d_in[0];
    float* out = (float*)d_out;

    // workspace layout (8192 each): idx1, idx2, rank1, rank2, w1, w2
    int*   idx1  = (int*)d_ws;
    int*   idx2  = idx1 + S;
    int*   rank1 = idx2 + S;
    int*   rank2 = rank1 + S;
    float* w1    = (float*)(rank2 + S);
    float* w2    = w1 + S;

    softmax_top2<<<S / 4, dim3(64, 4), 0, stream>>>(in, idx1, idx2, w1, w2);
    rank_kernel<<<E, 64, 0, stream>>>(idx1, idx2, rank1, rank2);
    fill_scatter<<<S, 256, 0, stream>>>(idx1, idx2, w1, w2, rank1, rank2, out);
}